// Round 11
// baseline (146.961 us; speedup 1.0000x reference)
//
#include <hip/hip_runtime.h>
#include <cfloat>
#include <cstddef>
#include <cstdint>

#define BATCH 8
#define CDIM  256
#define NTOK  2304   // 48*48

typedef float    f32x4 __attribute__((ext_vector_type(4)));
typedef _Float16 f16x8 __attribute__((ext_vector_type(8)));
typedef _Float16 f16x4 __attribute__((ext_vector_type(4)));

#define MFMA16(a, b, c) __builtin_amdgcn_mfma_f32_16x16x32_f16(a, b, c, 0, 0, 0)

__device__ __forceinline__ void gl_lds16(const void* g, void* l) {
    __builtin_amdgcn_global_load_lds(
        (const __attribute__((address_space(1))) void*)g,
        (__attribute__((address_space(3))) void*)l, 16, 0, 0);
}

// ---------------------------------------------------------------------------
// cast_w: Wq|Wk|Wv fp32 -> Wh fp16 [3][256][256]   (unchanged, verified)
// ---------------------------------------------------------------------------
__global__ __launch_bounds__(256) void cast_w(
    const float* __restrict__ Wq, const float* __restrict__ Wk,
    const float* __restrict__ Wv, _Float16* __restrict__ Wh)
{
    int i = (blockIdx.x * 256 + threadIdx.x) * 4;
    const float* src = (i < 65536) ? (Wq + i)
                     : (i < 131072) ? (Wk + (i - 65536)) : (Wv + (i - 131072));
    float4 v = *(const float4*)src;
    f16x4 h = { (_Float16)v.x, (_Float16)v.y, (_Float16)v.z, (_Float16)v.w };
    *(f16x4*)(Wh + i) = h;
}

// ---------------------------------------------------------------------------
// cast_x: x [B,C,N] fp32 -> Xt [B,N,C] fp16   (unchanged, verified)
// ---------------------------------------------------------------------------
__global__ __launch_bounds__(256) void cast_x(
    const float* __restrict__ x1, const float* __restrict__ x2,
    _Float16* __restrict__ Xt1, _Float16* __restrict__ Xt2)
{
    const int tid = threadIdx.x;
    const int n0 = blockIdx.x * 64;
    const int c0 = blockIdx.y * 64;
    const int bz = blockIdx.z;
    const float* X   = (bz < 8) ? x1 : x2;
    _Float16*   Xt   = (bz < 8) ? Xt1 : Xt2;
    const int b = bz & 7;

    __shared__ _Float16 T[64][72];

    {
        const int cl = tid >> 2, nch = (tid & 3) * 16;
        const float* src = X + (size_t)(b * CDIM + c0 + cl) * NTOK + n0 + nch;
#pragma unroll
        for (int u = 0; u < 4; ++u) {
            float4 v = *(const float4*)(src + u * 4);
            T[cl][nch + u * 4 + 0] = (_Float16)v.x;
            T[cl][nch + u * 4 + 1] = (_Float16)v.y;
            T[cl][nch + u * 4 + 2] = (_Float16)v.z;
            T[cl][nch + u * 4 + 3] = (_Float16)v.w;
        }
    }
    __syncthreads();
    {
        const int nl = tid >> 2, cch = (tid & 3) * 16;
        _Float16* dst = Xt + (size_t)(b * NTOK + n0 + nl) * CDIM + c0 + cch;
        f16x8 o0, o1;
#pragma unroll
        for (int i = 0; i < 8; ++i) {
            o0[i] = T[cch + i][nl];
            o1[i] = T[cch + 8 + i][nl];
        }
        *(f16x8*)dst = o0;
        *(f16x8*)(dst + 8) = o1;
    }
}

// ---------------------------------------------------------------------------
// proj_mfma   (unchanged, verified)
// ---------------------------------------------------------------------------
__global__ __launch_bounds__(256, 2) void proj_mfma(
    const _Float16* __restrict__ Xt1, const _Float16* __restrict__ Xt2,
    const _Float16* __restrict__ Wh,
    const float* __restrict__ bq, const float* __restrict__ bk,
    const float* __restrict__ bv,
    _Float16* __restrict__ Qo, _Float16* __restrict__ Ko, _Float16* __restrict__ Vo)
{
    const int tid  = threadIdx.x;
    const int lane = tid & 63;
    const int w    = tid >> 6;
    const int l15  = lane & 15, l4 = lane >> 4;
    const int n0   = blockIdx.x * 64;
    const int mode = blockIdx.y;
    const int b    = blockIdx.z;

    const _Float16* Xt = (mode == 0) ? Xt1 : Xt2;
    const _Float16* Wm = Wh + mode * 65536;
    const float* bias  = (mode == 0) ? bq : (mode == 1) ? bk : bv;
    _Float16* OUT      = (mode == 0) ? Qo : (mode == 1) ? Ko : Vo;

    __shared__ __align__(16) char sm[65536];
    _Float16* Xl = (_Float16*)sm;
    _Float16* Wl = (_Float16*)(sm + 32768);

#pragma unroll
    for (int t = 0; t < 8; ++t) {
        int i = w * 8 + t;
        int row = 2 * i + (lane >> 5);
        int ch  = lane & 31;
        gl_lds16(Xt + (size_t)(b * NTOK + n0 + row) * CDIM + ((ch ^ (row & 7)) * 8),
                 (char*)Xl + i * 1024);
    }

    float bias_o[4];
#pragma unroll
    for (int ot = 0; ot < 4; ++ot) bias_o[ot] = bias[w * 64 + ot * 16 + l15];

    f32x4 acc[16];
#pragma unroll
    for (int i = 0; i < 16; ++i) acc[i] = (f32x4){0.f, 0.f, 0.f, 0.f};

    for (int c0 = 0; c0 < CDIM; c0 += 64) {
        __syncthreads();
#pragma unroll
        for (int t = 0; t < 8; ++t) {
            int i = w * 8 + t;
            int row = 8 * i + (lane >> 3);
            int ch  = lane & 7;
            gl_lds16(Wm + (size_t)row * CDIM + c0 + ((ch ^ (row & 7)) * 8),
                     (char*)Wl + i * 1024);
        }
        __syncthreads();

#pragma unroll
        for (int kk2 = 0; kk2 < 2; ++kk2) {
            f16x8 a[4], bf[4];
#pragma unroll
            for (int nt = 0; nt < 4; ++nt) {
                int row = nt * 16 + l15;
                int ch  = ((c0 >> 3) + kk2 * 4 + l4) ^ (row & 7);
                a[nt] = *(const f16x8*)((const char*)Xl + row * 512 + ch * 16);
            }
#pragma unroll
            for (int ot = 0; ot < 4; ++ot) {
                int row = w * 64 + ot * 16 + l15;
                int ch  = (kk2 * 4 + l4) ^ (row & 7);
                bf[ot] = *(const f16x8*)((const char*)Wl + row * 128 + ch * 16);
            }
#pragma unroll
            for (int nt = 0; nt < 4; ++nt)
#pragma unroll
                for (int ot = 0; ot < 4; ++ot)
                    acc[nt * 4 + ot] = MFMA16(a[nt], bf[ot], acc[nt * 4 + ot]);
        }
    }

    __syncthreads();

    if (mode <= 1) {
        _Float16* Dl = (_Float16*)sm;
#pragma unroll
        for (int nt = 0; nt < 4; ++nt)
#pragma unroll
            for (int ot = 0; ot < 4; ++ot)
#pragma unroll
                for (int reg = 0; reg < 4; ++reg)
                    Dl[(nt * 16 + 4 * l4 + reg) * 256 + w * 64 + ot * 16 + l15] =
                        (_Float16)(acc[nt * 4 + ot][reg] + bias_o[ot]);
        __syncthreads();
        char* dst = (char*)(OUT + ((size_t)b * NTOK + n0) * CDIM);
#pragma unroll
        for (int u = 0; u < 8; ++u) {
            f16x8 v = *(const f16x8*)((const char*)Dl + u * 4096 + tid * 16);
            *(f16x8*)(dst + u * 4096 + tid * 16) = v;
        }
    } else {
        _Float16* Dlv = (_Float16*)sm;   // [256][80]
#pragma unroll
        for (int nt = 0; nt < 4; ++nt)
#pragma unroll
            for (int ot = 0; ot < 4; ++ot)
#pragma unroll
                for (int reg = 0; reg < 4; ++reg)
                    Dlv[(w * 64 + ot * 16 + l15) * 80 + nt * 16 + 4 * l4 + reg] =
                        (_Float16)(acc[nt * 4 + ot][reg] + bias_o[ot]);
        __syncthreads();
#pragma unroll
        for (int t = 0; t < 8; ++t) {
            int ro = (w * 8 + t) * 8 + (lane >> 3);
            f16x8 v = *(const f16x8*)((const char*)Dlv + ro * 160 + (lane & 7) * 16);
            *(f16x8*)(OUT + ((size_t)b * CDIM + ro) * NTOK + n0 + (lane & 7) * 8) = v;
        }
    }
}

// ---------------------------------------------------------------------------
// Split-KV MFMA flash attention — swapped-operand (verified r10) with
// 32 q-rows/wave: each kf/vb LDS read feeds TWO MFMAs (lo/hi q-sets),
// halving LDS-read volume per unit work. Block = 8 waves x 32 q = 256 q.
// Grid 9 x-tiles x 8 b x SEG=3 = 216 blocks -> ONE generation, no tail.
// sigma K-row permutation, defer-max, l-via-MFMA: all verified, per-set.
// ---------------------------------------------------------------------------
template <int SEG>
__global__ __launch_bounds__(512, 2) void attn_fa(
    const _Float16* __restrict__ Q, const _Float16* __restrict__ K,
    const _Float16* __restrict__ Vt, _Float16* __restrict__ pacc,
    float2* __restrict__ pml)
{
    const int tid  = threadIdx.x;
    const int lane = tid & 63;
    const int w    = tid >> 6;
    const int l15  = lane & 15, l4 = lane >> 4;

    // bijective XCD-chunked swizzle (grid % 8 == 0)
    const int nb  = 9 * BATCH * SEG, cpx = nb / 8;
    const int bid = blockIdx.x;
    const int swz = (bid & 7) * cpx + (bid >> 3);
    const int x = swz % 9;
    const int b = (swz / 9) & 7;
    const int z = swz / 72;

    const int row0   = x * 256 + w * 32;
    const int jbase  = z * (NTOK / SEG);
    const int NTILES = NTOK / SEG / 64;

    __shared__ __align__(16) char smem[131072];   // 128KB

    const size_t kbb = (size_t)b * NTOK;
    const size_t vbb = (size_t)b * CDIM * NTOK;

    auto stage = [&](int j0, int buf) {
        char* Klc = smem + buf * 65536;
        char* Vlc = Klc + 32768;
        // K: LDS row lr holds GLOBAL row sigma(lr); rows contiguous 512B.
#pragma unroll
        for (int t = 0; t < 4; ++t) {
            int i  = w * 4 + t;
            int lr = 2 * i + (lane >> 5);
            int gr = (lr & 32) | ((lr & 12) << 1) | ((lr & 16) >> 2) | (lr & 3);
            int chunk = lane & 31;
            gl_lds16(K + (kbb + j0 + gr) * CDIM + ((chunk ^ (lr & 7)) * 8),
                     Klc + i * 1024);
        }
        // V: linear j columns, c-row swizzle (verified).
#pragma unroll
        for (int t = 0; t < 4; ++t) {
            int i = w * 4 + t;
            int vrow = 8 * i + (lane >> 3);
            int chunk = lane & 7;
            gl_lds16(Vt + vbb + (size_t)vrow * NTOK + j0 + ((chunk ^ (vrow & 7)) * 8),
                     Vlc + i * 1024);
        }
    };

    // Q fragments: 2 sets of 16 rows x 256 c (nontemporal single-use stream)
    f16x8 qa_lo[8], qa_hi[8];
    {
        const _Float16* qb = Q + ((size_t)b * NTOK + row0 + l15) * CDIM + l4 * 8;
#pragma unroll
        for (int kk = 0; kk < 8; ++kk) {
            qa_lo[kk] = __builtin_nontemporal_load((const f16x8*)(qb + kk * 32));
            qa_hi[kk] = __builtin_nontemporal_load(
                            (const f16x8*)(qb + 16 * CDIM + kk * 32));
        }
    }

    f32x4 acc_lo[16], acc_hi[16];
#pragma unroll
    for (int ct = 0; ct < 16; ++ct) {
        acc_lo[ct] = (f32x4){0.f, 0.f, 0.f, 0.f};
        acc_hi[ct] = (f32x4){0.f, 0.f, 0.f, 0.f};
    }
    f32x4 accl_lo = (f32x4){0.f, 0.f, 0.f, 0.f};
    f32x4 accl_hi = (f32x4){0.f, 0.f, 0.f, 0.f};
    float m_lo = -FLT_MAX, m_hi = -FLT_MAX;

    const f16x8 vone = {(_Float16)1.f, (_Float16)1.f, (_Float16)1.f, (_Float16)1.f,
                        (_Float16)1.f, (_Float16)1.f, (_Float16)1.f, (_Float16)1.f};

    stage(jbase, 0);
    __syncthreads();

    for (int jt = 0; jt < NTILES; ++jt) {
        const int cur = jt & 1;

        if (jt + 1 < NTILES) stage(jbase + (jt + 1) * 64, cur ^ 1);

        const char* Klc = (const char*)smem + cur * 65536;
        const char* Vlc = Klc + 32768;

        // ---- QK^T swapped: each kf feeds lo and hi ----
        f32x4 s_lo[4], s_hi[4];
#pragma unroll
        for (int nt = 0; nt < 4; ++nt) {
            const char* kb = Klc + (nt * 16 + l15) * 512;
            f32x4 sl = (f32x4){0.f, 0.f, 0.f, 0.f};
            f32x4 sh = (f32x4){0.f, 0.f, 0.f, 0.f};
#pragma unroll
            for (int kk = 0; kk < 8; ++kk) {
                f16x8 kf = *(const f16x8*)(kb + (((kk * 4 + l4) ^ (l15 & 7)) * 16));
                sl = MFMA16(kf, qa_lo[kk], sl);
                sh = MFMA16(kf, qa_hi[kk], sh);
            }
            s_lo[nt] = sl;
            s_hi[nt] = sh;
        }

        // ---- softmax lo: lane-local chain + 2 shfl; defer-max THR=8 ----
        f16x8 pa_lo[2], pa_hi[2];
        {
            float pm = fmaxf(fmaxf(s_lo[0][0], s_lo[0][1]), fmaxf(s_lo[0][2], s_lo[0][3]));
            pm = fmaxf(pm, fmaxf(fmaxf(s_lo[1][0], s_lo[1][1]), fmaxf(s_lo[1][2], s_lo[1][3])));
            pm = fmaxf(pm, fmaxf(fmaxf(s_lo[2][0], s_lo[2][1]), fmaxf(s_lo[2][2], s_lo[2][3])));
            pm = fmaxf(pm, fmaxf(fmaxf(s_lo[3][0], s_lo[3][1]), fmaxf(s_lo[3][2], s_lo[3][3])));
            pm = fmaxf(pm, __shfl_xor(pm, 16));
            pm = fmaxf(pm, __shfl_xor(pm, 32));
            if (pm > m_lo + 8.f) {
                float sc = __expf(m_lo - pm);
                m_lo = pm;
#pragma unroll
                for (int e = 0; e < 4; ++e) accl_lo[e] *= sc;
#pragma unroll
                for (int ct = 0; ct < 16; ++ct)
#pragma unroll
                    for (int e = 0; e < 4; ++e) acc_lo[ct][e] *= sc;
            }
#pragma unroll
            for (int kc = 0; kc < 2; ++kc)
#pragma unroll
                for (int e = 0; e < 8; ++e)
                    pa_lo[kc][e] =
                        (_Float16)__expf(s_lo[2 * kc + (e >> 2)][e & 3] - m_lo);
        }
        // ---- softmax hi ----
        {
            float pm = fmaxf(fmaxf(s_hi[0][0], s_hi[0][1]), fmaxf(s_hi[0][2], s_hi[0][3]));
            pm = fmaxf(pm, fmaxf(fmaxf(s_hi[1][0], s_hi[1][1]), fmaxf(s_hi[1][2], s_hi[1][3])));
            pm = fmaxf(pm, fmaxf(fmaxf(s_hi[2][0], s_hi[2][1]), fmaxf(s_hi[2][2], s_hi[2][3])));
            pm = fmaxf(pm, fmaxf(fmaxf(s_hi[3][0], s_hi[3][1]), fmaxf(s_hi[3][2], s_hi[3][3])));
            pm = fmaxf(pm, __shfl_xor(pm, 16));
            pm = fmaxf(pm, __shfl_xor(pm, 32));
            if (pm > m_hi + 8.f) {
                float sc = __expf(m_hi - pm);
                m_hi = pm;
#pragma unroll
                for (int e = 0; e < 4; ++e) accl_hi[e] *= sc;
#pragma unroll
                for (int ct = 0; ct < 16; ++ct)
#pragma unroll
                    for (int e = 0; e < 4; ++e) acc_hi[ct][e] *= sc;
            }
#pragma unroll
            for (int kc = 0; kc < 2; ++kc)
#pragma unroll
                for (int e = 0; e < 8; ++e)
                    pa_hi[kc][e] =
                        (_Float16)__expf(s_hi[2 * kc + (e >> 2)][e & 3] - m_hi);
        }

        // ---- l and PV: each vb feeds lo and hi ----
        accl_lo = MFMA16(vone, pa_lo[0], accl_lo);
        accl_lo = MFMA16(vone, pa_lo[1], accl_lo);
        accl_hi = MFMA16(vone, pa_hi[0], accl_hi);
        accl_hi = MFMA16(vone, pa_hi[1], accl_hi);
#pragma unroll
        for (int ct = 0; ct < 16; ++ct) {
            const char* vb0 = Vlc + (ct * 16 + l15) * 128;
#pragma unroll
            for (int kc = 0; kc < 2; ++kc) {
                f16x8 vb = *(const f16x8*)(vb0 + (((kc * 4 + l4) ^ (l15 & 7)) * 16));
                acc_lo[ct] = MFMA16(vb, pa_lo[kc], acc_lo[ct]);
                acc_hi[ct] = MFMA16(vb, pa_hi[kc], acc_hi[ct]);
            }
        }

        __syncthreads();
    }

    // ---- epilogue: two 16-row passes through wave-private stg (verified) ----
    _Float16* stg = (_Float16*)(smem + w * 8448);
    const size_t pbase = ((size_t)z * BATCH + b) * NTOK * CDIM;
    // pass lo
    {
        float inv = 1.f / accl_lo[0];
#pragma unroll
        for (int ct = 0; ct < 16; ++ct) {
            f16x4 o = { (_Float16)(acc_lo[ct][0] * inv), (_Float16)(acc_lo[ct][1] * inv),
                        (_Float16)(acc_lo[ct][2] * inv), (_Float16)(acc_lo[ct][3] * inv) };
            *(f16x4*)&stg[l15 * 264 + ct * 16 + l4 * 4] = o;
        }
        if (l4 == 0)
            pml[((size_t)z * BATCH + b) * NTOK + row0 + l15] =
                make_float2(m_lo, accl_lo[0]);
    }
    asm volatile("s_waitcnt lgkmcnt(0)" ::: "memory");
    __builtin_amdgcn_sched_barrier(0);
    {
        const char* stgc = (const char*)stg;
        char* dst = (char*)(pacc + pbase + (size_t)row0 * CDIM);
#pragma unroll
        for (int u = 0; u < 8; ++u) {
            int r = 2 * u + (lane >> 5);
            f16x8 v = *(const f16x8*)(stgc + r * 528 + (lane & 31) * 16);
            *(f16x8*)(dst + r * 512 + (lane & 31) * 16) = v;
        }
    }
    asm volatile("s_waitcnt lgkmcnt(0)" ::: "memory");
    __builtin_amdgcn_sched_barrier(0);
    // pass hi
    {
        float inv = 1.f / accl_hi[0];
#pragma unroll
        for (int ct = 0; ct < 16; ++ct) {
            f16x4 o = { (_Float16)(acc_hi[ct][0] * inv), (_Float16)(acc_hi[ct][1] * inv),
                        (_Float16)(acc_hi[ct][2] * inv), (_Float16)(acc_hi[ct][3] * inv) };
            *(f16x4*)&stg[l15 * 264 + ct * 16 + l4 * 4] = o;
        }
        if (l4 == 0)
            pml[((size_t)z * BATCH + b) * NTOK + row0 + 16 + l15] =
                make_float2(m_hi, accl_hi[0]);
    }
    asm volatile("s_waitcnt lgkmcnt(0)" ::: "memory");
    __builtin_amdgcn_sched_barrier(0);
    {
        const char* stgc = (const char*)stg;
        char* dst = (char*)(pacc + pbase + (size_t)(row0 + 16) * CDIM);
#pragma unroll
        for (int u = 0; u < 8; ++u) {
            int r = 2 * u + (lane >> 5);
            f16x8 v = *(const f16x8*)(stgc + r * 528 + (lane & 31) * 16);
            *(f16x8*)(dst + r * 512 + (lane & 31) * 16) = v;
        }
    }
}

// ---------------------------------------------------------------------------
// Merge (unchanged, verified)
// ---------------------------------------------------------------------------
template <int SEG>
__global__ __launch_bounds__(256) void merge_kernel(
    const _Float16* __restrict__ pacc, const float2* __restrict__ pml,
    float* __restrict__ out)
{
    const int tid = threadIdx.x;
    const int n0 = blockIdx.x * 64;
    const int b  = blockIdx.y;

    __shared__ float wgt[SEG][64];
    __shared__ float dinv[64];
    __shared__ float T[64][68];

    if (tid < 64) {
        int n = n0 + tid;
        float ms[SEG], ls[SEG];
#pragma unroll
        for (int s = 0; s < SEG; ++s) {
            float2 v = pml[((size_t)s * BATCH + b) * NTOK + n];
            ms[s] = v.x; ls[s] = v.y;
        }
        float M = ms[0];
#pragma unroll
        for (int s = 1; s < SEG; ++s) M = fmaxf(M, ms[s]);
        float den = 0.f;
#pragma unroll
        for (int s = 0; s < SEG; ++s) {
            float g = ls[s] * __expf(ms[s] - M);
            wgt[s][tid] = g;
            den += g;
        }
        dinv[tid] = 1.f / den;
    }
    __syncthreads();

    for (int cc = 0; cc < 4; ++cc) {
        const int nl = tid >> 2, cg = (tid & 3) * 16;
        float a[16];
#pragma unroll
        for (int u = 0; u < 16; ++u) a[u] = 0.f;
#pragma unroll
        for (int s = 0; s < SEG; ++s) {
            const _Float16* p = pacc + (((size_t)s * BATCH + b) * NTOK + n0 + nl) * CDIM
                                + cc * 64 + cg;
            f16x8 v0 = ((const f16x8*)p)[0];
            f16x8 v1 = ((const f16x8*)p)[1];
            float g = wgt[s][nl];
#pragma unroll
            for (int u = 0; u < 8; ++u) {
                a[u]     += g * (float)v0[u];
                a[8 + u] += g * (float)v1[u];
            }
        }
        float di = dinv[nl];
#pragma unroll
        for (int u = 0; u < 16; ++u) T[nl][cg + u] = a[u] * di;
        __syncthreads();

        const int cl = tid >> 2, nb2 = (tid & 3) * 16;
        float* ob = out + ((size_t)b * CDIM + cc * 64 + cl) * NTOK + n0 + nb2;
#pragma unroll
        for (int u = 0; u < 4; ++u) {
            float4 v = { T[nb2 + u * 4 + 0][cl], T[nb2 + u * 4 + 1][cl],
                         T[nb2 + u * 4 + 2][cl], T[nb2 + u * 4 + 3][cl] };
            *(float4*)&ob[u * 4] = v;
        }
        __syncthreads();
    }
}

// ---------------------------------------------------------------------------
extern "C" void kernel_launch(void* const* d_in, const int* in_sizes, int n_in,
                              void* d_out, int out_size, void* d_ws, size_t ws_size,
                              hipStream_t stream)
{
    const float* x1 = (const float*)d_in[0];
    const float* x2 = (const float*)d_in[1];
    const float* Wq = (const float*)d_in[2];
    const float* bq = (const float*)d_in[3];
    const float* Wk = (const float*)d_in[4];
    const float* bk = (const float*)d_in[5];
    const float* Wv = (const float*)d_in[6];
    const float* bv = (const float*)d_in[7];
    float* out = (float*)d_out;

    const size_t plane = (size_t)BATCH * NTOK * CDIM;   // 4,718,592
    _Float16* ws16 = (_Float16*)d_ws;
    _Float16* Q   = ws16;
    _Float16* K   = ws16 + plane;
    _Float16* Vt  = ws16 + 2 * plane;
    _Float16* Xt1 = ws16 + 3 * plane;
    _Float16* Xt2 = ws16 + 4 * plane;
    _Float16* Wh  = ws16 + 5 * plane;
    const size_t fixed16 = 5 * plane + 196608;

    auto need = [&](size_t S) {
        return fixed16 * 2 + S * plane * 2 + S * (size_t)BATCH * NTOK * 8;
    };
    const int SEG = (ws_size >= need(3)) ? 3 : (ws_size >= need(2)) ? 2 : 1;

    _Float16* pacc = ws16 + fixed16;
    float2*   pml  = (float2*)((char*)d_ws + fixed16 * 2 + (size_t)SEG * plane * 2);

    cast_w<<<dim3(192), dim3(256), 0, stream>>>(Wq, Wk, Wv, Wh);
    cast_x<<<dim3(36, 4, 16), dim3(256), 0, stream>>>(x1, x2, Xt1, Xt2);
    proj_mfma<<<dim3(36, 3, BATCH), dim3(256), 0, stream>>>(
        Xt1, Xt2, Wh, bq, bk, bv, Q, K, Vt);

    const int nb = 9 * BATCH;
    if (SEG == 3) {
        attn_fa<3><<<dim3(nb * 3), dim3(512), 0, stream>>>(Q, K, Vt, pacc, pml);
        merge_kernel<3><<<dim3(36, BATCH), dim3(256), 0, stream>>>(pacc, pml, out);
    } else if (SEG == 2) {
        attn_fa<2><<<dim3(nb * 2), dim3(512), 0, stream>>>(Q, K, Vt, pacc, pml);
        merge_kernel<2><<<dim3(36, BATCH), dim3(256), 0, stream>>>(pacc, pml, out);
    } else {
        attn_fa<1><<<dim3(nb), dim3(512), 0, stream>>>(Q, K, Vt, pacc, pml);
        merge_kernel<1><<<dim3(36, BATCH), dim3(256), 0, stream>>>(pacc, pml, out);
    }
}

// Round 12
// 116.110 us; speedup vs baseline: 1.2657x; 1.2657x over previous
//
#include <hip/hip_runtime.h>
#include <cfloat>
#include <cstddef>
#include <cstdint>

#define BATCH 8
#define CDIM  256
#define NTOK  2304   // 48*48

typedef float    f32x4 __attribute__((ext_vector_type(4)));
typedef _Float16 f16x8 __attribute__((ext_vector_type(8)));
typedef _Float16 f16x4 __attribute__((ext_vector_type(4)));

#define MFMA16(a, b, c) __builtin_amdgcn_mfma_f32_16x16x32_f16(a, b, c, 0, 0, 0)

__device__ __forceinline__ void gl_lds16(const void* g, void* l) {
    __builtin_amdgcn_global_load_lds(
        (const __attribute__((address_space(1))) void*)g,
        (__attribute__((address_space(3))) void*)l, 16, 0, 0);
}

// ---------------------------------------------------------------------------
// cast_fused: one launch does both
//   blocks [0,192):   Wq|Wk|Wv fp32 -> Wh fp16 [3][256][256]
//   blocks [192,...): x [B,C,N] fp32 -> Xt [B,N,C] fp16 (64x64 LDS transpose)
// Bodies identical to the verified cast_w / cast_x kernels.
// ---------------------------------------------------------------------------
__global__ __launch_bounds__(256) void cast_fused(
    const float* __restrict__ x1, const float* __restrict__ x2,
    const float* __restrict__ Wq, const float* __restrict__ Wk,
    const float* __restrict__ Wv,
    _Float16* __restrict__ Xt1, _Float16* __restrict__ Xt2,
    _Float16* __restrict__ Wh)
{
    const int tid = threadIdx.x;
    int bx = blockIdx.x;

    if (bx < 192) {
        int i = (bx * 256 + tid) * 4;
        const float* src = (i < 65536) ? (Wq + i)
                         : (i < 131072) ? (Wk + (i - 65536)) : (Wv + (i - 131072));
        float4 v = *(const float4*)src;
        f16x4 h = { (_Float16)v.x, (_Float16)v.y, (_Float16)v.z, (_Float16)v.w };
        *(f16x4*)(Wh + i) = h;
        return;
    }
    bx -= 192;
    const int n0 = (bx % 36) * 64;
    const int rest = bx / 36;
    const int c0 = (rest & 3) * 64;
    const int bz = rest >> 2;
    const float* X   = (bz < 8) ? x1 : x2;
    _Float16*   Xt   = (bz < 8) ? Xt1 : Xt2;
    const int b = bz & 7;

    __shared__ _Float16 T[64][72];

    {
        const int cl = tid >> 2, nch = (tid & 3) * 16;
        const float* src = X + (size_t)(b * CDIM + c0 + cl) * NTOK + n0 + nch;
#pragma unroll
        for (int u = 0; u < 4; ++u) {
            float4 v = *(const float4*)(src + u * 4);
            T[cl][nch + u * 4 + 0] = (_Float16)v.x;
            T[cl][nch + u * 4 + 1] = (_Float16)v.y;
            T[cl][nch + u * 4 + 2] = (_Float16)v.z;
            T[cl][nch + u * 4 + 3] = (_Float16)v.w;
        }
    }
    __syncthreads();
    {
        const int nl = tid >> 2, cch = (tid & 3) * 16;
        _Float16* dst = Xt + (size_t)(b * NTOK + n0 + nl) * CDIM + c0 + cch;
        f16x8 o0, o1;
#pragma unroll
        for (int i = 0; i < 8; ++i) {
            o0[i] = T[cch + i][nl];
            o1[i] = T[cch + 8 + i][nl];
        }
        *(f16x8*)dst = o0;
        *(f16x8*)(dst + 8) = o1;
    }
}

// ---------------------------------------------------------------------------
// proj_mfma   (unchanged, verified)
// ---------------------------------------------------------------------------
__global__ __launch_bounds__(256, 2) void proj_mfma(
    const _Float16* __restrict__ Xt1, const _Float16* __restrict__ Xt2,
    const _Float16* __restrict__ Wh,
    const float* __restrict__ bq, const float* __restrict__ bk,
    const float* __restrict__ bv,
    _Float16* __restrict__ Qo, _Float16* __restrict__ Ko, _Float16* __restrict__ Vo)
{
    const int tid  = threadIdx.x;
    const int lane = tid & 63;
    const int w    = tid >> 6;
    const int l15  = lane & 15, l4 = lane >> 4;
    const int n0   = blockIdx.x * 64;
    const int mode = blockIdx.y;
    const int b    = blockIdx.z;

    const _Float16* Xt = (mode == 0) ? Xt1 : Xt2;
    const _Float16* Wm = Wh + mode * 65536;
    const float* bias  = (mode == 0) ? bq : (mode == 1) ? bk : bv;
    _Float16* OUT      = (mode == 0) ? Qo : (mode == 1) ? Ko : Vo;

    __shared__ __align__(16) char sm[65536];
    _Float16* Xl = (_Float16*)sm;
    _Float16* Wl = (_Float16*)(sm + 32768);

#pragma unroll
    for (int t = 0; t < 8; ++t) {
        int i = w * 8 + t;
        int row = 2 * i + (lane >> 5);
        int ch  = lane & 31;
        gl_lds16(Xt + (size_t)(b * NTOK + n0 + row) * CDIM + ((ch ^ (row & 7)) * 8),
                 (char*)Xl + i * 1024);
    }

    float bias_o[4];
#pragma unroll
    for (int ot = 0; ot < 4; ++ot) bias_o[ot] = bias[w * 64 + ot * 16 + l15];

    f32x4 acc[16];
#pragma unroll
    for (int i = 0; i < 16; ++i) acc[i] = (f32x4){0.f, 0.f, 0.f, 0.f};

    for (int c0 = 0; c0 < CDIM; c0 += 64) {
        __syncthreads();
#pragma unroll
        for (int t = 0; t < 8; ++t) {
            int i = w * 8 + t;
            int row = 8 * i + (lane >> 3);
            int ch  = lane & 7;
            gl_lds16(Wm + (size_t)row * CDIM + c0 + ((ch ^ (row & 7)) * 8),
                     (char*)Wl + i * 1024);
        }
        __syncthreads();

#pragma unroll
        for (int kk2 = 0; kk2 < 2; ++kk2) {
            f16x8 a[4], bf[4];
#pragma unroll
            for (int nt = 0; nt < 4; ++nt) {
                int row = nt * 16 + l15;
                int ch  = ((c0 >> 3) + kk2 * 4 + l4) ^ (row & 7);
                a[nt] = *(const f16x8*)((const char*)Xl + row * 512 + ch * 16);
            }
#pragma unroll
            for (int ot = 0; ot < 4; ++ot) {
                int row = w * 64 + ot * 16 + l15;
                int ch  = (kk2 * 4 + l4) ^ (row & 7);
                bf[ot] = *(const f16x8*)((const char*)Wl + row * 128 + ch * 16);
            }
#pragma unroll
            for (int nt = 0; nt < 4; ++nt)
#pragma unroll
                for (int ot = 0; ot < 4; ++ot)
                    acc[nt * 4 + ot] = MFMA16(a[nt], bf[ot], acc[nt * 4 + ot]);
        }
    }

    __syncthreads();

    if (mode <= 1) {
        _Float16* Dl = (_Float16*)sm;
#pragma unroll
        for (int nt = 0; nt < 4; ++nt)
#pragma unroll
            for (int ot = 0; ot < 4; ++ot)
#pragma unroll
                for (int reg = 0; reg < 4; ++reg)
                    Dl[(nt * 16 + 4 * l4 + reg) * 256 + w * 64 + ot * 16 + l15] =
                        (_Float16)(acc[nt * 4 + ot][reg] + bias_o[ot]);
        __syncthreads();
        char* dst = (char*)(OUT + ((size_t)b * NTOK + n0) * CDIM);
#pragma unroll
        for (int u = 0; u < 8; ++u) {
            f16x8 v = *(const f16x8*)((const char*)Dl + u * 4096 + tid * 16);
            *(f16x8*)(dst + u * 4096 + tid * 16) = v;
        }
    } else {
        _Float16* Dlv = (_Float16*)sm;   // [256][80]
#pragma unroll
        for (int nt = 0; nt < 4; ++nt)
#pragma unroll
            for (int ot = 0; ot < 4; ++ot)
#pragma unroll
                for (int reg = 0; reg < 4; ++reg)
                    Dlv[(w * 64 + ot * 16 + l15) * 80 + nt * 16 + 4 * l4 + reg] =
                        (_Float16)(acc[nt * 4 + ot][reg] + bias_o[ot]);
        __syncthreads();
#pragma unroll
        for (int t = 0; t < 8; ++t) {
            int ro = (w * 8 + t) * 8 + (lane >> 3);
            f16x8 v = *(const f16x8*)((const char*)Dlv + ro * 160 + (lane & 7) * 16);
            *(f16x8*)(OUT + ((size_t)b * CDIM + ro) * NTOK + n0 + (lane & 7) * 8) = v;
        }
    }
}

// ---------------------------------------------------------------------------
// Split-KV MFMA flash attention — EXACT r10 structure (verified 80.7us):
// swapped-operand, sigma K-row permutation, no P LDS, l-via-MFMA, defer-max,
// 16 q/wave, KVBLK=64 dbuf, 128KB LDS. Only delta: T5 setprio around the
// MFMA clusters (wave drift within iterations gives role diversity).
// ---------------------------------------------------------------------------
template <int SEG>
__global__ __launch_bounds__(512, 2) void attn_fa(
    const _Float16* __restrict__ Q, const _Float16* __restrict__ K,
    const _Float16* __restrict__ Vt, _Float16* __restrict__ pacc,
    float2* __restrict__ pml)
{
    const int tid  = threadIdx.x;
    const int lane = tid & 63;
    const int w    = tid >> 6;
    const int l15  = lane & 15, l4 = lane >> 4;

    // bijective XCD-chunked swizzle (grid % 8 == 0)
    const int nb  = 18 * BATCH * SEG, cpx = nb / 8;
    const int bid = blockIdx.x;
    const int swz = (bid & 7) * cpx + (bid >> 3);
    const int x = swz % 18;
    const int b = (swz / 18) & 7;
    const int z = swz / 144;

    const int row0   = x * 128 + w * 16;
    const int jbase  = z * (NTOK / SEG);
    const int NTILES = NTOK / SEG / 64;

    __shared__ __align__(16) char smem[131072];   // 128KB

    const size_t kbb = (size_t)b * NTOK;
    const size_t vbb = (size_t)b * CDIM * NTOK;

    auto stage = [&](int j0, int buf) {
        char* Klc = smem + buf * 65536;
        char* Vlc = Klc + 32768;
        // K: LDS row lr holds GLOBAL row sigma(lr); rows contiguous 512B.
#pragma unroll
        for (int t = 0; t < 4; ++t) {
            int i  = w * 4 + t;
            int lr = 2 * i + (lane >> 5);
            int gr = (lr & 32) | ((lr & 12) << 1) | ((lr & 16) >> 2) | (lr & 3);
            int chunk = lane & 31;
            gl_lds16(K + (kbb + j0 + gr) * CDIM + ((chunk ^ (lr & 7)) * 8),
                     Klc + i * 1024);
        }
        // V: linear j columns, c-row swizzle (verified).
#pragma unroll
        for (int t = 0; t < 4; ++t) {
            int i = w * 4 + t;
            int vrow = 8 * i + (lane >> 3);
            int chunk = lane & 7;
            gl_lds16(Vt + vbb + (size_t)vrow * NTOK + j0 + ((chunk ^ (vrow & 7)) * 8),
                     Vlc + i * 1024);
        }
    };

    // Q fragments: 16 rows x 256 c (nontemporal single-use stream)
    f16x8 qa[8];
    {
        const _Float16* qb = Q + ((size_t)b * NTOK + row0 + l15) * CDIM + l4 * 8;
#pragma unroll
        for (int kk = 0; kk < 8; ++kk)
            qa[kk] = __builtin_nontemporal_load((const f16x8*)(qb + kk * 32));
    }

    f32x4 acc[16];
#pragma unroll
    for (int ct = 0; ct < 16; ++ct) acc[ct] = (f32x4){0.f, 0.f, 0.f, 0.f};
    f32x4 accl = (f32x4){0.f, 0.f, 0.f, 0.f};
    float m = -FLT_MAX;                     // per-lane: q = row0 + l15

    const f16x8 vone = {(_Float16)1.f, (_Float16)1.f, (_Float16)1.f, (_Float16)1.f,
                        (_Float16)1.f, (_Float16)1.f, (_Float16)1.f, (_Float16)1.f};

    stage(jbase, 0);
    __syncthreads();

    for (int jt = 0; jt < NTILES; ++jt) {
        const int cur = jt & 1;

        if (jt + 1 < NTILES) stage(jbase + (jt + 1) * 64, cur ^ 1);

        const char* Klc = (const char*)smem + cur * 65536;
        const char* Vlc = Klc + 32768;

        // ---- QK^T swapped: s[nt] = S^T[label = nt*16+4*l4+reg][q = l15] ----
        f32x4 s[4];
        __builtin_amdgcn_s_setprio(1);
#pragma unroll
        for (int nt = 0; nt < 4; ++nt) {
            const char* kb = Klc + (nt * 16 + l15) * 512;
            f32x4 sv = (f32x4){0.f, 0.f, 0.f, 0.f};
#pragma unroll
            for (int kk = 0; kk < 8; ++kk) {
                f16x8 kf = *(const f16x8*)(kb + (((kk * 4 + l4) ^ (l15 & 7)) * 16));
                sv = MFMA16(kf, qa[kk], sv);        // SWAPPED
            }
            s[nt] = sv;
        }
        __builtin_amdgcn_s_setprio(0);

        // ---- softmax: lane-local max chain + 2 shfl; defer-max THR=8 ----
        float pm = fmaxf(fmaxf(s[0][0], s[0][1]), fmaxf(s[0][2], s[0][3]));
        pm = fmaxf(pm, fmaxf(fmaxf(s[1][0], s[1][1]), fmaxf(s[1][2], s[1][3])));
        pm = fmaxf(pm, fmaxf(fmaxf(s[2][0], s[2][1]), fmaxf(s[2][2], s[2][3])));
        pm = fmaxf(pm, fmaxf(fmaxf(s[3][0], s[3][1]), fmaxf(s[3][2], s[3][3])));
        pm = fmaxf(pm, __shfl_xor(pm, 16));
        pm = fmaxf(pm, __shfl_xor(pm, 32));
        if (pm > m + 8.f) {
            float sc = __expf(m - pm);
            m = pm;
#pragma unroll
            for (int e = 0; e < 4; ++e) accl[e] *= sc;
#pragma unroll
            for (int ct = 0; ct < 16; ++ct)
#pragma unroll
                for (int e = 0; e < 4; ++e) acc[ct][e] *= sc;
        }

        // ---- P in registers (lane-local, via K-row permutation) ----
        f16x8 pa[2];
#pragma unroll
        for (int kc = 0; kc < 2; ++kc)
#pragma unroll
            for (int e = 0; e < 8; ++e)
                pa[kc][e] = (_Float16)__expf(s[2 * kc + (e >> 2)][e & 3] - m);

        // ---- l and PV (both swapped: acc (c = 4*l4+reg, q = l15)) ----
        __builtin_amdgcn_s_setprio(1);
        accl = MFMA16(vone, pa[0], accl);
        accl = MFMA16(vone, pa[1], accl);
#pragma unroll
        for (int ct = 0; ct < 16; ++ct) {
            const char* vb0 = Vlc + (ct * 16 + l15) * 128;
#pragma unroll
            for (int kc = 0; kc < 2; ++kc) {
                f16x8 vb = *(const f16x8*)(vb0 + (((kc * 4 + l4) ^ (l15 & 7)) * 16));
                acc[ct] = MFMA16(vb, pa[kc], acc[ct]);   // SWAPPED
            }
        }
        __builtin_amdgcn_s_setprio(0);

        __syncthreads();
    }

    // ---- epilogue: stg [16 q][264 f16] (padded) -> linear pacc stores ----
    _Float16* stg = (_Float16*)(smem + w * 8448);
    {
        float inv = 1.f / accl[0];
#pragma unroll
        for (int ct = 0; ct < 16; ++ct) {
            f16x4 o = { (_Float16)(acc[ct][0] * inv), (_Float16)(acc[ct][1] * inv),
                        (_Float16)(acc[ct][2] * inv), (_Float16)(acc[ct][3] * inv) };
            *(f16x4*)&stg[l15 * 264 + ct * 16 + l4 * 4] = o;
        }
        if (l4 == 0)
            pml[((size_t)z * BATCH + b) * NTOK + row0 + l15] =
                make_float2(m, accl[0]);
    }
    asm volatile("s_waitcnt lgkmcnt(0)" ::: "memory");
    __builtin_amdgcn_sched_barrier(0);
    {
        const char* stgc = (const char*)stg;
        char* dst = (char*)(pacc + ((size_t)z * BATCH + b) * NTOK * CDIM
                            + (size_t)row0 * CDIM);
#pragma unroll
        for (int u = 0; u < 8; ++u) {
            int r = 2 * u + (lane >> 5);
            f16x8 v = *(const f16x8*)(stgc + r * 528 + (lane & 31) * 16);
            *(f16x8*)(dst + r * 512 + (lane & 31) * 16) = v;
        }
    }
}

// ---------------------------------------------------------------------------
// Merge — cc moved into the grid (x4 parallelism, no serial cc loop).
// out[b][c][n] = sum_s w_s * ohat_s[n][c] / sum_s w_s,  w_s = l_s e^(m_s-M)
// ---------------------------------------------------------------------------
template <int SEG>
__global__ __launch_bounds__(256) void merge_kernel(
    const _Float16* __restrict__ pacc, const float2* __restrict__ pml,
    float* __restrict__ out)
{
    const int tid = threadIdx.x;
    const int n0 = blockIdx.x * 64;
    const int cc = blockIdx.y;
    const int b  = blockIdx.z;

    __shared__ float wgt[SEG][64];
    __shared__ float dinv[64];
    __shared__ float T[64][68];

    if (tid < 64) {
        int n = n0 + tid;
        float ms[SEG], ls[SEG];
#pragma unroll
        for (int s = 0; s < SEG; ++s) {
            float2 v = pml[((size_t)s * BATCH + b) * NTOK + n];
            ms[s] = v.x; ls[s] = v.y;
        }
        float M = ms[0];
#pragma unroll
        for (int s = 1; s < SEG; ++s) M = fmaxf(M, ms[s]);
        float den = 0.f;
#pragma unroll
        for (int s = 0; s < SEG; ++s) {
            float g = ls[s] * __expf(ms[s] - M);
            wgt[s][tid] = g;
            den += g;
        }
        dinv[tid] = 1.f / den;
    }
    __syncthreads();

    {
        const int nl = tid >> 2, cg = (tid & 3) * 16;
        float a[16];
#pragma unroll
        for (int u = 0; u < 16; ++u) a[u] = 0.f;
#pragma unroll
        for (int s = 0; s < SEG; ++s) {
            const _Float16* p = pacc + (((size_t)s * BATCH + b) * NTOK + n0 + nl) * CDIM
                                + cc * 64 + cg;
            f16x8 v0 = ((const f16x8*)p)[0];
            f16x8 v1 = ((const f16x8*)p)[1];
            float g = wgt[s][nl];
#pragma unroll
            for (int u = 0; u < 8; ++u) {
                a[u]     += g * (float)v0[u];
                a[8 + u] += g * (float)v1[u];
            }
        }
        float di = dinv[nl];
#pragma unroll
        for (int u = 0; u < 16; ++u) T[nl][cg + u] = a[u] * di;
    }
    __syncthreads();
    {
        const int cl = tid >> 2, nb2 = (tid & 3) * 16;
        float* ob = out + ((size_t)b * CDIM + cc * 64 + cl) * NTOK + n0 + nb2;
#pragma unroll
        for (int u = 0; u < 4; ++u) {
            float4 v = { T[nb2 + u * 4 + 0][cl], T[nb2 + u * 4 + 1][cl],
                         T[nb2 + u * 4 + 2][cl], T[nb2 + u * 4 + 3][cl] };
            *(float4*)&ob[u * 4] = v;
        }
    }
}

// ---------------------------------------------------------------------------
extern "C" void kernel_launch(void* const* d_in, const int* in_sizes, int n_in,
                              void* d_out, int out_size, void* d_ws, size_t ws_size,
                              hipStream_t stream)
{
    const float* x1 = (const float*)d_in[0];
    const float* x2 = (const float*)d_in[1];
    const float* Wq = (const float*)d_in[2];
    const float* bq = (const float*)d_in[3];
    const float* Wk = (const float*)d_in[4];
    const float* bk = (const float*)d_in[5];
    const float* Wv = (const float*)d_in[6];
    const float* bv = (const float*)d_in[7];
    float* out = (float*)d_out;

    const size_t plane = (size_t)BATCH * NTOK * CDIM;   // 4,718,592
    _Float16* ws16 = (_Float16*)d_ws;
    _Float16* Q   = ws16;
    _Float16* K   = ws16 + plane;
    _Float16* Vt  = ws16 + 2 * plane;
    _Float16* Xt1 = ws16 + 3 * plane;
    _Float16* Xt2 = ws16 + 4 * plane;
    _Float16* Wh  = ws16 + 5 * plane;
    const size_t fixed16 = 5 * plane + 196608;

    auto need = [&](size_t S) {
        return fixed16 * 2 + S * plane * 2 + S * (size_t)BATCH * NTOK * 8;
    };
    const int SEG = (ws_size >= need(3)) ? 3 : (ws_size >= need(2)) ? 2 : 1;

    _Float16* pacc = ws16 + fixed16;
    float2*   pml  = (float2*)((char*)d_ws + fixed16 * 2 + (size_t)SEG * plane * 2);

    cast_fused<<<dim3(192 + 36 * 4 * 16), dim3(256), 0, stream>>>(
        x1, x2, Wq, Wk, Wv, Xt1, Xt2, Wh);
    proj_mfma<<<dim3(36, 3, BATCH), dim3(256), 0, stream>>>(
        Xt1, Xt2, Wh, bq, bk, bv, Q, K, Vt);

    const int nb = 18 * BATCH;
    if (SEG == 3) {
        attn_fa<3><<<dim3(nb * 3), dim3(512), 0, stream>>>(Q, K, Vt, pacc, pml);
        merge_kernel<3><<<dim3(36, 4, BATCH), dim3(256), 0, stream>>>(pacc, pml, out);
    } else if (SEG == 2) {
        attn_fa<2><<<dim3(nb * 2), dim3(512), 0, stream>>>(Q, K, Vt, pacc, pml);
        merge_kernel<2><<<dim3(36, 4, BATCH), dim3(256), 0, stream>>>(pacc, pml, out);
    } else {
        attn_fa<1><<<dim3(nb), dim3(512), 0, stream>>>(Q, K, Vt, pacc, pml);
        merge_kernel<1><<<dim3(36, 4, BATCH), dim3(256), 0, stream>>>(pacc, pml, out);
    }
}